// Round 14
// baseline (734.402 us; speedup 1.0000x reference)
//
#include <hip/hip_runtime.h>
#include <hip/hip_bf16.h>
#include <stdio.h>

// BNBQuantizedLinear: out = x @ dequant(w)^T + bias
// x [8192,4096] f32, w [11008,4096] f32 (group-128 affine fake-quant), out f32.
// Round 14: BARRIER-FREE, LDS-FREE GEMM. r13's cycle model (accurate to 3%):
// VMEM + DS + MFMA pipes are fully ADDITIVE in every barrier-synced structure
// (8 waves convoy through mem-phase -> MFMA-phase). Fix: both operands in
// fragment-major workspace layouts (A' new, B' since r12); each wave does 12
// coalesced 1KB reg-loads + 32 MFMA per K64-tile with zero barriers/LDS ->
// waves desync and VMEM overlaps MFMA across waves (m114). Load-use distance
// = 1 tile (~2000cyc >> L2 latency). All waits are compiler register deps.
// Epilogue: r13's coalesced per-wave LDS transpose (private region, no bar).

typedef signed char i8;
typedef unsigned int u32;
typedef unsigned long long u64;
typedef __attribute__((ext_vector_type(4))) int i32x4;
typedef __attribute__((ext_vector_type(4))) float f32x4;

constexpr int Mdim = 8192;
constexpr int Ndim = 11008;
constexpr int Kdim = 4096;

__device__ __forceinline__ int q_i8(float v, float mult) {
  float q = rintf(v * mult);
  q = fmaxf(-127.0f, fminf(127.0f, q));
  return (int)q;
}

// ---------------- kernel 1: weight -> residual int8 (fragment-major B') + row mean ----------------
// Identical to r12/r13 (verified absmax 6.0).
__global__ __launch_bounds__(512) void k_prep_w(const float* __restrict__ w,
                                                i8* __restrict__ w8,
                                                float* __restrict__ mu) {
  const int o = blockIdx.x;
  const int t = threadIdx.x;
  const int g = t >> 4;
  __shared__ float s_sc[32], s_mn[32], s_gmu[32];
  __shared__ float s_mu;

  const float* wr = w + (size_t)o * Kdim + t * 8;
  const float4 v0 = *(const float4*)wr;
  const float4 v1 = *(const float4*)(wr + 4);
  float v[8] = {v0.x, v0.y, v0.z, v0.w, v1.x, v1.y, v1.z, v1.w};

  float mn = v[0], mx = v[0], sm = 0.0f;
#pragma unroll
  for (int j = 0; j < 8; ++j) {
    mn = fminf(mn, v[j]); mx = fmaxf(mx, v[j]); sm += v[j];
  }
#pragma unroll
  for (int off = 1; off < 16; off <<= 1) {
    mn = fminf(mn, __shfl_xor(mn, off));
    mx = fmaxf(mx, __shfl_xor(mx, off));
    sm += __shfl_xor(sm, off);
  }
  if ((t & 15) == 0) {
    const float sc = (mx - mn) * (1.0f / 15.0f);
    s_sc[g] = sc;
    s_mn[g] = mn;
    s_gmu[g] = sc * (sm * (1.0f / 128.0f)) + mn;
  }
  __syncthreads();
  if (t == 0) {
    float s = 0.0f;
#pragma unroll
    for (int c = 0; c < 32; ++c) s += s_gmu[c];
    s_mu = s * (1.0f / 32.0f);
    mu[o] = s_mu;
  }
  __syncthreads();
  const float sc = s_sc[g], mnv = s_mn[g], m = s_mu;
  const float mult = 127.0f / 4.5f;
  u32 lo = 0, hi = 0;
#pragma unroll
  for (int j = 0; j < 4; ++j) {
    const float wd = v[j] * sc + mnv;
    lo |= ((u32)(q_i8(wd - m, mult) & 0xff)) << (8 * j);
  }
#pragma unroll
  for (int j = 0; j < 4; ++j) {
    const float wd = v[4 + j] * sc + mnv;
    hi |= ((u32)(q_i8(wd - m, mult) & 0xff)) << (8 * j);
  }
  const size_t dst = ((size_t)(o >> 4) * 64 + (t >> 3)) * 1024
                   + (size_t)(((t >> 1) & 3) * 16 + (o & 15)) * 16
                   + (size_t)(t & 1) * 8;
  *(u64*)(w8 + dst) = (u64)lo | ((u64)hi << 32);
}

// ---------------- kernel 2: x -> int8 fragment-major A' + exact f32 row sums ----------------
// Same quant math as r9-r13; write address now fragment-major (same formula
// family as k_prep_w): A'[((m>>4)*64 + tau)*1024 + (kg*16 + (m&15))*16 + half*8].
__global__ __launch_bounds__(512) void k_prep_x(const float* __restrict__ x,
                                                i8* __restrict__ x8,
                                                float* __restrict__ X) {
  const int m = blockIdx.x;
  const int t = threadIdx.x;
  __shared__ float s_ws[8];
  const float* xr = x + (size_t)m * Kdim + t * 8;
  const float4 v0 = *(const float4*)xr;
  const float4 v1 = *(const float4*)(xr + 4);
  float v[8] = {v0.x, v0.y, v0.z, v0.w, v1.x, v1.y, v1.z, v1.w};
  float sm = 0.0f;
#pragma unroll
  for (int j = 0; j < 8; ++j) sm += v[j];
  const float mult = 127.0f / 6.0f;
  u32 lo = 0, hi = 0;
#pragma unroll
  for (int j = 0; j < 4; ++j) lo |= ((u32)(q_i8(v[j], mult) & 0xff)) << (8 * j);
#pragma unroll
  for (int j = 0; j < 4; ++j) hi |= ((u32)(q_i8(v[4 + j], mult) & 0xff)) << (8 * j);
  const size_t dst = ((size_t)(m >> 4) * 64 + (t >> 3)) * 1024
                   + (size_t)(((t >> 1) & 3) * 16 + (m & 15)) * 16
                   + (size_t)(t & 1) * 8;
  *(u64*)(x8 + dst) = (u64)lo | ((u64)hi << 32);
#pragma unroll
  for (int off = 1; off < 64; off <<= 1) sm += __shfl_xor(sm, off);
  if ((t & 63) == 0) s_ws[t >> 6] = sm;
  __syncthreads();
  if (t == 0) {
    float s = 0.0f;
#pragma unroll
    for (int wv = 0; wv < 8; ++wv) s += s_ws[wv];
    X[m] = s;
  }
}

// ---------------- kernel 3: barrier-free int8 GEMM, both operands reg-streamed ----------------
__global__ __launch_bounds__(512) void k_gemm(const i8* __restrict__ Ap,
                                              const i8* __restrict__ Bp,
                                              const float* __restrict__ bias,
                                              const float* __restrict__ mu,
                                              const float* __restrict__ X,
                                              float* __restrict__ C) {
  __shared__ float eplds[8 * 2048];   // 64 KB, epilogue only (per-wave private)

  const int t = threadIdx.x;
  const int wave = t >> 6;        // 0..7
  const int lane = t & 63;
  const int wm = wave >> 2;       // 2(M) x 4(N); wave owns 128x64 out
  const int wn = wave & 3;
  const int r  = lane & 15;
  const int kg = lane >> 4;

  // bijective XCD swizzle: 1376 workgroups = 8 XCDs x 172
  const int bid = blockIdx.x;
  const int wg = (bid & 7) * 172 + (bid >> 3);
  const int by = wg / 43;
  const int bx = wg % 43;
  const long bm0 = (long)by * 256;
  const long bn0 = (long)bx * 256;

  // fragment streams: lane reads 16B at (blk16*64 + tau)*1024 + lane*16.
  const i8* a_frag = Ap + ((size_t)(by * 16 + wm * 8)) * 65536 + (size_t)lane * 16;
  const i8* b_frag = Bp + ((size_t)(bx * 16 + wn * 4)) * 65536 + (size_t)lane * 16;

  i32x4 acc[8][4] = {};
  i32x4 aF[8];          // A frags, reloaded in place right after last use
  i32x4 bP[4], bQ[4];   // B frags, ping-pong by tile parity

  // TILE(OFF): MFMA on aF/BCUR (tile OFF/1024); prefetch tile OFF/1024+1 into
  // BNXT and (in place, after each mf group's last use) aF. All hazards are
  // per-wave register deps: compiler inserts vmcnt before first consuming
  // MFMA; WAR (reload over aF[mf]) cannot be hoisted above its reader.
#define TILE(OFF, BCUR, BNXT, PREF) do {                                     \
    if (PREF) {                                                              \
      _Pragma("unroll")                                                      \
      for (int nf = 0; nf < 4; ++nf)                                         \
        BNXT[nf] = *(const i32x4*)(b_frag + (size_t)nf * 65536 + (OFF) + 1024); \
    }                                                                        \
    _Pragma("unroll")                                                        \
    for (int mf = 0; mf < 8; ++mf) {                                         \
      _Pragma("unroll")                                                      \
      for (int nf = 0; nf < 4; ++nf)                                         \
        acc[mf][nf] = __builtin_amdgcn_mfma_i32_16x16x64_i8(aF[mf], BCUR[nf], acc[mf][nf], 0, 0, 0); \
      if (PREF) aF[mf] = *(const i32x4*)(a_frag + (size_t)mf * 65536 + (OFF) + 1024); \
    }                                                                        \
  } while (0)

  // prologue: tile 0 into aF/bP
#pragma unroll
  for (int mf = 0; mf < 8; ++mf) aF[mf] = *(const i32x4*)(a_frag + (size_t)mf * 65536);
#pragma unroll
  for (int nf = 0; nf < 4; ++nf) bP[nf] = *(const i32x4*)(b_frag + (size_t)nf * 65536);

  size_t off = 0;
  for (int it = 0; it < 31; ++it, off += 2048) {
    TILE(off, bP, bQ, 1);
    TILE(off + 1024, bQ, bP, 1);
  }
  // off == 62*1024
  TILE(off, bP, bQ, 1);          // tile 62, prefetch 63
  TILE(off + 1024, bQ, bP, 0);   // tile 63

  // ---- coalesced epilogue (r13, verified): per-wave LDS transpose ----
  // C/D layout: lane (kg,r) holds acc[mf][nf][j] = C(mf*16+kg*4+j, nf*16+r).
  // Swizzle col' = col ^ 16*((row>>2)&3); writer mask 16*kg == reader 16*(i&3).
  float* wls = eplds + wave * 2048;
  const float sxsw = (6.0f / 127.0f) * (4.5f / 127.0f);
  float bv[4], mv[4];
#pragma unroll
  for (int nf = 0; nf < 4; ++nf) {
    const long col = bn0 + wn * 64 + nf * 16 + r;
    bv[nf] = bias[col];
    mv[nf] = mu[col];
  }
  const long crow0 = bm0 + wm * 128;
  const long ccol0 = bn0 + wn * 64;
#pragma unroll
  for (int p = 0; p < 4; ++p) {
#pragma unroll
    for (int mh = 0; mh < 2; ++mh) {
      const int mf = 2 * p + mh;
      const long rowg0 = crow0 + mf * 16 + kg * 4;
      float xv[4];
#pragma unroll
      for (int j = 0; j < 4; ++j) xv[j] = X[rowg0 + j];
#pragma unroll
      for (int nf = 0; nf < 4; ++nf) {
        const int c = nf * 16 + r;
        const int lr0 = mh * 16 + kg * 4;
#pragma unroll
        for (int j = 0; j < 4; ++j) {
          const float val = sxsw * (float)acc[mf][nf][j] + mv[nf] * xv[j] + bv[nf];
          wls[(lr0 + j) * 64 + (c ^ (kg * 16))] = val;
        }
      }
    }
#pragma unroll
    for (int i = 0; i < 8; ++i) {
      const int rowl = 4 * i + (lane >> 4);
      const int c0 = (lane & 15) * 4;
      const f32x4 v = *(const f32x4*)&wls[rowl * 64 + (c0 ^ ((i & 3) * 16))];
      const long rowg = crow0 + p * 32 + rowl;
      *(f32x4*)&C[rowg * Ndim + ccol0 + c0] = v;
    }
  }
}

extern "C" void kernel_launch(void* const* d_in, const int* in_sizes, int n_in,
                              void* d_out, int out_size, void* d_ws, size_t ws_size,
                              hipStream_t stream) {
  const float* x    = (const float*)d_in[0];
  const float* w    = (const float*)d_in[1];
  const float* bias = (const float*)d_in[2];
  float* out = (float*)d_out;

  const size_t xb_bytes = (size_t)Mdim * Kdim;   // A' fragment-major
  const size_t wb_bytes = (size_t)Ndim * Kdim;   // B' fragment-major
  const size_t off_X  = xb_bytes + wb_bytes;
  const size_t off_mu = off_X + (size_t)Mdim * 4;
  const size_t need   = off_mu + (size_t)Ndim * 4;
  if (ws_size < need) {
    fprintf(stderr, "kernel_launch: ws too small (%zu < %zu)\n", ws_size, need);
    return;
  }
  i8* xb8 = (i8*)d_ws;
  i8* wb8 = xb8 + xb_bytes;
  float* Xs = (float*)((char*)d_ws + off_X);
  float* muW = (float*)((char*)d_ws + off_mu);

  k_prep_w<<<Ndim, 512, 0, stream>>>(w, wb8, muW);
  k_prep_x<<<Mdim, 512, 0, stream>>>(x, xb8, Xs);

  // grid: 43 N-tiles x 32 M-tiles = 1376 blocks (divisible by 8 XCDs)
  k_gemm<<<(Ndim / 256) * (Mdim / 256), 512, 0, stream>>>(xb8, wb8, bias, muW, Xs, out);
}

// Round 15
// 494.052 us; speedup vs baseline: 1.4865x; 1.4865x over previous
//
#include <hip/hip_runtime.h>
#include <hip/hip_bf16.h>
#include <stdio.h>

// BNBQuantizedLinear: out = x @ dequant(w)^T + bias
// x [8192,4096] f32, w [11008,4096] f32 (group-128 affine fake-quant), out f32.
// Round 15 = REVERT to round 13 (best verified: 493us total, k_gemm 420us,
// absmax 6.0). Round 14's barrier-free experiment falsified the last overlap
// hypothesis: per-CU time = VMEM + DS + MFMA additively in ALL 8 tested
// structures; r13 measures ~99% of that additive floor (2930 vs ~2970
// cyc/tile: VMEM ~900 + DS 768 + MFMA_i8 1306).
// Structure: int8 MFMA 16x16x64 (zero-mean residual quant + exact rank-1
// mean correction), A via 4-ring LDS (source-pre-swizzled global_load_lds,
// 0 bank conflicts), fragment-major B' streamed to regs (coalesced 1KB
// wave-loads), 1 barrier/tile, bijective XCD swizzle, coalesced epilogue
// via per-wave LDS transpose (WRITE_SIZE 352MB = ideal).

typedef signed char i8;
typedef unsigned int u32;
typedef unsigned long long u64;
typedef __attribute__((ext_vector_type(4))) int i32x4;
typedef __attribute__((ext_vector_type(4))) float f32x4;

constexpr int Mdim = 8192;
constexpr int Ndim = 11008;
constexpr int Kdim = 4096;

#define NT64 64             // K tiles of 64
#define TEB 16384           // bytes per A K-tile buffer: 256 rows x 64 B

__device__ __forceinline__ int q_i8(float v, float mult) {
  float q = rintf(v * mult);
  q = fmaxf(-127.0f, fminf(127.0f, q));
  return (int)q;
}

// ---------------- kernel 1: weight -> residual int8 (fragment-major) + row mean ----------------
__global__ __launch_bounds__(512) void k_prep_w(const float* __restrict__ w,
                                                i8* __restrict__ w8,
                                                float* __restrict__ mu) {
  const int o = blockIdx.x;
  const int t = threadIdx.x;
  const int g = t >> 4;
  __shared__ float s_sc[32], s_mn[32], s_gmu[32];
  __shared__ float s_mu;

  const float* wr = w + (size_t)o * Kdim + t * 8;
  const float4 v0 = *(const float4*)wr;
  const float4 v1 = *(const float4*)(wr + 4);
  float v[8] = {v0.x, v0.y, v0.z, v0.w, v1.x, v1.y, v1.z, v1.w};

  float mn = v[0], mx = v[0], sm = 0.0f;
#pragma unroll
  for (int j = 0; j < 8; ++j) {
    mn = fminf(mn, v[j]); mx = fmaxf(mx, v[j]); sm += v[j];
  }
#pragma unroll
  for (int off = 1; off < 16; off <<= 1) {
    mn = fminf(mn, __shfl_xor(mn, off));
    mx = fmaxf(mx, __shfl_xor(mx, off));
    sm += __shfl_xor(sm, off);
  }
  if ((t & 15) == 0) {
    const float sc = (mx - mn) * (1.0f / 15.0f);
    s_sc[g] = sc;
    s_mn[g] = mn;
    s_gmu[g] = sc * (sm * (1.0f / 128.0f)) + mn;
  }
  __syncthreads();
  if (t == 0) {
    float s = 0.0f;
#pragma unroll
    for (int c = 0; c < 32; ++c) s += s_gmu[c];
    s_mu = s * (1.0f / 32.0f);
    mu[o] = s_mu;
  }
  __syncthreads();
  const float sc = s_sc[g], mnv = s_mn[g], m = s_mu;
  const float mult = 127.0f / 4.5f;
  u32 lo = 0, hi = 0;
#pragma unroll
  for (int j = 0; j < 4; ++j) {
    const float wd = v[j] * sc + mnv;
    lo |= ((u32)(q_i8(wd - m, mult) & 0xff)) << (8 * j);
  }
#pragma unroll
  for (int j = 0; j < 4; ++j) {
    const float wd = v[4 + j] * sc + mnv;
    hi |= ((u32)(q_i8(wd - m, mult) & 0xff)) << (8 * j);
  }
  const size_t dst = ((size_t)(o >> 4) * 64 + (t >> 3)) * 1024
                   + (size_t)(((t >> 1) & 3) * 16 + (o & 15)) * 16
                   + (size_t)(t & 1) * 8;
  *(u64*)(w8 + dst) = (u64)lo | ((u64)hi << 32);
}

// ---------------- kernel 2: x -> int8 + exact f32 row sums ----------------
__global__ __launch_bounds__(512) void k_prep_x(const float* __restrict__ x,
                                                i8* __restrict__ x8,
                                                float* __restrict__ X) {
  const int m = blockIdx.x;
  const int t = threadIdx.x;
  __shared__ float s_ws[8];
  const float* xr = x + (size_t)m * Kdim + t * 8;
  const float4 v0 = *(const float4*)xr;
  const float4 v1 = *(const float4*)(xr + 4);
  float v[8] = {v0.x, v0.y, v0.z, v0.w, v1.x, v1.y, v1.z, v1.w};
  float sm = 0.0f;
#pragma unroll
  for (int j = 0; j < 8; ++j) sm += v[j];
  const float mult = 127.0f / 6.0f;
  u32 lo = 0, hi = 0;
#pragma unroll
  for (int j = 0; j < 4; ++j) lo |= ((u32)(q_i8(v[j], mult) & 0xff)) << (8 * j);
#pragma unroll
  for (int j = 0; j < 4; ++j) hi |= ((u32)(q_i8(v[4 + j], mult) & 0xff)) << (8 * j);
  u32* dst = (u32*)(x8 + (size_t)m * Kdim + t * 8);
  dst[0] = lo; dst[1] = hi;
#pragma unroll
  for (int off = 1; off < 64; off <<= 1) sm += __shfl_xor(sm, off);
  if ((t & 63) == 0) s_ws[t >> 6] = sm;
  __syncthreads();
  if (t == 0) {
    float s = 0.0f;
#pragma unroll
    for (int wv = 0; wv < 8; ++wv) s += s_ws[wv];
    X[m] = s;
  }
}

// ---------------- kernel 3: int8 GEMM, A via LDS ring, B' streamed, coalesced epilogue ----------------
__device__ __forceinline__ void async_ld16(const i8* g, i8* l) {
  __builtin_amdgcn_global_load_lds(
      (const __attribute__((address_space(1))) void*)g,
      (__attribute__((address_space(3))) void*)l, 16, 0, 0);
}

__global__ __launch_bounds__(512, 2) void k_gemm(const i8* __restrict__ A,
                                                 const i8* __restrict__ Bp,
                                                 const float* __restrict__ bias,
                                                 const float* __restrict__ mu,
                                                 const float* __restrict__ X,
                                                 float* __restrict__ C) {
  __shared__ i8 As[4 * TEB];   // 64 KB: 4-ring of A K-tiles; reused by epilogue

  const int t = threadIdx.x;
  const int wave = t >> 6;        // 0..7
  const int lane = t & 63;
  const int wm = wave >> 2;       // 2(M) x 4(N); wave owns 128x64 out
  const int wn = wave & 3;
  const int r  = lane & 15;
  const int kg = lane >> 4;       // K-group: 16 i8 each (K=64 total)
  const int slot = kg ^ ((r >> 1) & 3);   // A LDS-read swizzle (involution with
                                          // staging pre-XOR -> natural k)

  // bijective XCD swizzle: 1376 workgroups = 8 XCDs x 172
  const int bid = blockIdx.x;
  const int wg = (bid & 7) * 172 + (bid >> 3);
  const int by = wg / 43;
  const int bx = wg % 43;
  const long bm0 = (long)by * 256;
  const long bn0 = (long)bx * 256;

  // A staging: one issue = 512 thr x 16B = 8 KB = 128 rows x 64 B; 2 per tile.
  const int s_row  = t >> 2;
  const int s_slot = (t & 3) ^ ((t >> 3) & 3);
  const i8* a_src = A + (bm0 + s_row) * Kdim + s_slot * 16;
  const int st_off = wave * 1024;

  const int a_roff = (wm * 128 + r) * 64 + slot * 16;  // bytes; + mf*1024

  // B' fragment stream (fragment-major, coalesced)
  const i8* b_frag = Bp + ((size_t)bx * 16 + wn * 4) * 65536 + (size_t)lane * 16;

  i32x4 acc[8][4] = {};
  i32x4 bsA[4], bsB[4];   // B reg sets, ping-pong by tile parity

#define STAGE_A(TAU, BUF) do {                                    \
    const i8* ga_ = a_src + (size_t)(TAU) * 64;                   \
    i8* la_ = As + (BUF) * TEB + st_off;                          \
    async_ld16(ga_,                       la_);                   \
    async_ld16(ga_ + (size_t)128 * Kdim,  la_ + 8192);            \
  } while (0)

#define LOADB(TAU, DST) do {                                      \
    const i8* gb_ = b_frag + (size_t)(TAU) * 1024;                \
    _Pragma("unroll")                                             \
    for (int nf = 0; nf < 4; ++nf)                                \
      DST[nf] = *(const i32x4*)(gb_ + (size_t)nf * 65536);        \
  } while (0)

#define VM8 asm volatile("s_waitcnt vmcnt(8)" ::: "memory")
#define VMNONE (void)0

  // Hazard ledger (verified r12/r13):
  //  Per tile issue order: [A(t+3):2 gload_lds, B(t+1):4 reg-loads].
  //  MFMA(t) consumes B(t) (issued tile t-1, AFTER A(t+2)'s stage) -> compiler
  //  emits the vmcnt wait for B(t); in-order VMEM retirement then guarantees
  //  A(t+1)/A(t+2) drained per-wave BEFORE the MFMAs, hence before barrier(t)
  //  -> tile t+1's ds_reads safe on all waves.
  //  WAR: STAGE_A(t+3) -> ring slot (t-1)&3; its ds_reads completed before
  //  barrier(t-1). B reg ping-pong WAR compiler-tracked.
#define KTILE(TAU, BUF, BCUR, BLD, DO_STAGE, DO_LOAD) do {                   \
    if (DO_STAGE) STAGE_A((TAU) + 3, ((BUF) + 3) & 3);                       \
    if (DO_LOAD) LOADB((TAU) + 1, BLD);                                      \
    const i8* Ab_ = As + (BUF) * TEB;                                        \
    i32x4 af[8];                                                             \
    _Pragma("unroll")                                                        \
    for (int mf = 0; mf < 8; ++mf) af[mf] = *(const i32x4*)(Ab_ + a_roff + mf * 1024); \
    __builtin_amdgcn_s_setprio(1);                                           \
    _Pragma("unroll")                                                        \
    for (int mf = 0; mf < 8; ++mf)                                           \
      _Pragma("unroll")                                                      \
      for (int nf = 0; nf < 4; ++nf)                                         \
        acc[mf][nf] = __builtin_amdgcn_mfma_i32_16x16x64_i8(af[mf], BCUR[nf], acc[mf][nf], 0, 0, 0); \
    __builtin_amdgcn_s_setprio(0);                                           \
    __builtin_amdgcn_s_barrier();                                            \
  } while (0)

  // prologue: A tiles 0,1,2 staged; B tile 0 into bsA.
  STAGE_A(0, 0);
  STAGE_A(1, 1);
  STAGE_A(2, 2);
  LOADB(0, bsA);
  VM8;                    // outstanding [A0:2,A1:2,A2:2,B0:4]=10 -> drain A0
  __builtin_amdgcn_s_barrier();

  for (int tau = 0; tau < NT64 - 4; tau += 4) {
    KTILE(tau + 0, 0, bsA, bsB, 1, 1);
    KTILE(tau + 1, 1, bsB, bsA, 1, 1);
    KTILE(tau + 2, 2, bsA, bsB, 1, 1);
    KTILE(tau + 3, 3, bsB, bsA, 1, 1);
  }
  KTILE(60, 0, bsA, bsB, 1, 1);   // stages A63, loads B61
  KTILE(61, 1, bsB, bsA, 0, 1);   // loads B62 (B62 wait @62 drains A63)
  KTILE(62, 2, bsA, bsB, 0, 1);   // loads B63
  KTILE(63, 3, bsB, bsA, 0, 0);
  // final barrier passed: all waves' ds_reads of As are complete -> As is free.

  // ---- coalesced epilogue: per-wave LDS transpose, 4 passes of 32x64 f32 ----
  // C/D layout: lane (kg,r) holds acc[mf][nf][j] = C(mf*16+kg*4+j, nf*16+r)
  // within the wave's 128x64 block. Swizzle: col' = col ^ 16*((row>>2)&3);
  // writer's (row>>2)&3 == kg, reader's == (i&3) for rows 4i..4i+3 -> cancels.
  float* lds_f = (float*)As;                 // 8 KB = 2048 f32 per wave
  float* wls = lds_f + wave * 2048;
  const float sxsw = (6.0f / 127.0f) * (4.5f / 127.0f);
  float bv[4], mv[4];
#pragma unroll
  for (int nf = 0; nf < 4; ++nf) {
    const long col = bn0 + wn * 64 + nf * 16 + r;
    bv[nf] = bias[col];
    mv[nf] = mu[col];
  }
  const long crow0 = bm0 + wm * 128;
  const long ccol0 = bn0 + wn * 64;
#pragma unroll
  for (int p = 0; p < 4; ++p) {
#pragma unroll
    for (int mh = 0; mh < 2; ++mh) {
      const int mf = 2 * p + mh;
      const long rowg0 = crow0 + mf * 16 + kg * 4;
      float xv[4];
#pragma unroll
      for (int j = 0; j < 4; ++j) xv[j] = X[rowg0 + j];
#pragma unroll
      for (int nf = 0; nf < 4; ++nf) {
        const int c = nf * 16 + r;
        const int lr0 = mh * 16 + kg * 4;       // local row base (swz = 16*kg)
#pragma unroll
        for (int j = 0; j < 4; ++j) {
          const float val = sxsw * (float)acc[mf][nf][j] + mv[nf] * xv[j] + bv[nf];
          wls[(lr0 + j) * 64 + (c ^ (kg * 16))] = val;
        }
      }
    }
    // read back float4 (swz uniform per instr: 16*(i&3)) and store coalesced
#pragma unroll
    for (int i = 0; i < 8; ++i) {
      const int rowl = 4 * i + (lane >> 4);     // 0..31
      const int c0 = (lane & 15) * 4;
      const f32x4 v = *(const f32x4*)&wls[rowl * 64 + (c0 ^ ((i & 3) * 16))];
      const long rowg = crow0 + p * 32 + rowl;
      *(f32x4*)&C[rowg * Ndim + ccol0 + c0] = v;
    }
  }
}

extern "C" void kernel_launch(void* const* d_in, const int* in_sizes, int n_in,
                              void* d_out, int out_size, void* d_ws, size_t ws_size,
                              hipStream_t stream) {
  const float* x    = (const float*)d_in[0];
  const float* w    = (const float*)d_in[1];
  const float* bias = (const float*)d_in[2];
  float* out = (float*)d_out;

  const size_t xb_bytes = (size_t)Mdim * Kdim;
  const size_t wb_bytes = (size_t)Ndim * Kdim;   // B' fragment-major
  const size_t off_X  = xb_bytes + wb_bytes;
  const size_t off_mu = off_X + (size_t)Mdim * 4;
  const size_t need   = off_mu + (size_t)Ndim * 4;
  if (ws_size < need) {
    fprintf(stderr, "kernel_launch: ws too small (%zu < %zu)\n", ws_size, need);
    return;
  }
  i8* xb8 = (i8*)d_ws;
  i8* wb8 = xb8 + xb_bytes;
  float* Xs = (float*)((char*)d_ws + off_X);
  float* muW = (float*)((char*)d_ws + off_mu);

  k_prep_w<<<Ndim, 512, 0, stream>>>(w, wb8, muW);
  k_prep_x<<<Mdim, 512, 0, stream>>>(x, xb8, Xs);

  // grid: 43 N-tiles x 32 M-tiles = 1376 blocks (divisible by 8 XCDs)
  k_gemm<<<(Ndim / 256) * (Mdim / 256), 512, 0, stream>>>(xb8, wb8, bias, muW, Xs, out);
}